// Round 6
// baseline (1009.303 us; speedup 1.0000x reference)
//
#include <hip/hip_runtime.h>
#include <hip/hip_bf16.h>
#include <math.h>

#define N_NODES 100000
#define N_EDGES 1000000
#define NEG_SLOPE 0.2f
#define SCAN_NB 98  // ceil(100000/1024)

typedef short v8s __attribute__((ext_vector_type(8)));
typedef float v4f __attribute__((ext_vector_type(4)));

__device__ inline unsigned pack_bf16(float a, float b) {
    unsigned ua = __float_as_uint(a);
    unsigned ub = __float_as_uint(b);
    ua = (ua + 0x7FFFu + ((ua >> 16) & 1u)) >> 16;
    ub = (ub + 0x7FFFu + ((ub >> 16) & 1u)) >> 16;
    return ua | (ub << 16);
}
__device__ inline unsigned short bf16_rn(float x) {
    unsigned u = __float_as_uint(x);
    u = (u + 0x7FFFu + ((u >> 16) & 1u)) >> 16;
    return (unsigned short)u;
}
__device__ inline float2 unpk(unsigned u) {
    return make_float2(__uint_as_float(u << 16), __uint_as_float(u & 0xFFFF0000u));
}

// ---------------- CSR build ----------------
__global__ void hist_kernel(const int* __restrict__ dst, int* __restrict__ counts) {
    int e = blockIdx.x * blockDim.x + threadIdx.x;
    if (e < N_EDGES) atomicAdd(&counts[dst[e]], 1);
}

__global__ void scan_partial(const int* __restrict__ counts, int* __restrict__ bsum) {
    __shared__ int red[256];
    int b = blockIdx.x;
    int base = b * 1024;
    int s = 0;
    for (int i = threadIdx.x; i < 1024; i += 256) {
        int gi = base + i;
        s += (gi < N_NODES) ? counts[gi] : 0;
    }
    red[threadIdx.x] = s;
    __syncthreads();
    for (int off = 128; off > 0; off >>= 1) {
        if (threadIdx.x < off) red[threadIdx.x] += red[threadIdx.x + off];
        __syncthreads();
    }
    if (threadIdx.x == 0) bsum[b] = red[0];
}

__global__ void scan_bsum(const int* __restrict__ bsum, int* __restrict__ boff,
                          int* __restrict__ row_ptr) {
    __shared__ int s[128];
    int t = threadIdx.x;
    int v = (t < SCAN_NB) ? bsum[t] : 0;
    s[t] = v;
    __syncthreads();
    for (int off = 1; off < 128; off <<= 1) {
        int u = (t >= off) ? s[t - off] : 0;
        __syncthreads();
        s[t] += u;
        __syncthreads();
    }
    if (t < SCAN_NB) boff[t] = s[t] - v;
    if (t == 127) row_ptr[N_NODES] = s[127];
}

__global__ void scan_final(const int* __restrict__ counts, const int* __restrict__ boff,
                           int* __restrict__ row_ptr, int* __restrict__ cursor) {
    __shared__ int tsum[256];
    int b = blockIdx.x;
    int base = b * 1024;
    int v[4];
    int local = 0;
#pragma unroll
    for (int j = 0; j < 4; ++j) {
        int gi = base + threadIdx.x * 4 + j;
        v[j] = (gi < N_NODES) ? counts[gi] : 0;
        local += v[j];
    }
    tsum[threadIdx.x] = local;
    __syncthreads();
    for (int off = 1; off < 256; off <<= 1) {
        int u = (threadIdx.x >= off) ? tsum[threadIdx.x - off] : 0;
        __syncthreads();
        tsum[threadIdx.x] += u;
        __syncthreads();
    }
    int run = boff[b] + tsum[threadIdx.x] - local;
#pragma unroll
    for (int j = 0; j < 4; ++j) {
        int gi = base + threadIdx.x * 4 + j;
        if (gi < N_NODES) {
            row_ptr[gi] = run;
            cursor[gi] = run;
            run += v[j];
        }
    }
}

__global__ void scatter_kernel(const int* __restrict__ src, const int* __restrict__ dst,
                               int* __restrict__ cursor, int* __restrict__ srcs) {
    int e = blockIdx.x * blockDim.x + threadIdx.x;
    if (e < N_EDGES) {
        int pos = atomicAdd(&cursor[dst[e]], 1);
        srcs[pos] = src[e];
    }
}

// ---------------- weight convert: Wt[n=0..383][k] = W_sec[k*128 + n&127] (bf16)
template <int K>
__global__ void convert_w(const float* __restrict__ Wl, const float* __restrict__ Wr,
                          const float* __restrict__ Ws, unsigned short* __restrict__ wt) {
    int idx = blockIdx.x * blockDim.x + threadIdx.x;
    if (idx >= 384 * K) return;
    int n = idx / K;
    int k = idx - n * K;
    int sec = n >> 7;
    int nn = n & 127;
    const float* W = (sec == 0) ? Wl : (sec == 1) ? Wr : Ws;
    wt[idx] = bf16_rn(W[k * 128 + nn]);
}

// ---------------- h0 = relu(x @ W0) -> bf16 [N,32] ----------------
__global__ void h0_kernel(const float* __restrict__ x, const float* __restrict__ W0,
                          unsigned short* __restrict__ h) {
    int tid = blockIdx.x * blockDim.x + threadIdx.x;
    int col = tid & 31;
    int row = tid >> 5;
    if (row >= N_NODES) return;
    const float* xr = x + row * 64;
    float acc = 0.f;
#pragma unroll
    for (int k = 0; k < 64; ++k) acc = fmaf(xr[k], W0[k * 32 + col], acc);
    h[row * 32 + col] = bf16_rn(fmaxf(acc, 0.f));
}

// ---------------- MFMA mm3: [N,K]bf16 @ Wt^T -> xl|xr|skip all bf16 ----------------
// One block = 256 rows (4 waves x 64 rows). A-frags loaded ONCE into registers,
// then loop the 6 column-tiles (3 sections x 2 halves) streaming only Wt (L1/L2-hot).
template <int K>
__global__ __launch_bounds__(256) void mm3_mfma(
    const unsigned short* __restrict__ A, const unsigned short* __restrict__ Wt,
    const float* __restrict__ bl, const float* __restrict__ br, const float* __restrict__ bs,
    const float* __restrict__ cb,
    unsigned short* __restrict__ xl_bf, unsigned short* __restrict__ xr_bf,
    unsigned short* __restrict__ sk_bf) {
    const int tid = threadIdx.x;
    const int wave = tid >> 6;
    const int lane = tid & 63;
    const int q = lane >> 4;
    const int li = lane & 15;
    const int r0 = blockIdx.x * 256 + wave * 64;
    constexpr int KS = K / 32;

    // A fragments for 64 rows x K, resident in registers (K=128: 64 VGPRs)
    v8s a[4][KS];
#pragma unroll
    for (int mi = 0; mi < 4; ++mi) {
        int row = r0 + mi * 16 + li;
        row = row < N_NODES ? row : N_NODES - 1;
#pragma unroll
        for (int ks = 0; ks < KS; ++ks)
            a[mi][ks] = *(const v8s*)&A[(size_t)row * K + ks * 32 + q * 8];
    }

    for (int t = 0; t < 6; ++t) {
        const int sec = t >> 1;
        const int c0 = (t & 1) * 64;
        v4f acc[4][4];
#pragma unroll
        for (int mi = 0; mi < 4; ++mi)
#pragma unroll
            for (int ni = 0; ni < 4; ++ni) acc[mi][ni] = (v4f)(0.f);

#pragma unroll
        for (int ks = 0; ks < KS; ++ks) {
            v8s b[4];
#pragma unroll
            for (int ni = 0; ni < 4; ++ni) {
                int col = sec * 128 + c0 + ni * 16 + li;
                b[ni] = *(const v8s*)&Wt[(size_t)col * K + ks * 32 + q * 8];
            }
#pragma unroll
            for (int mi = 0; mi < 4; ++mi)
#pragma unroll
                for (int ni = 0; ni < 4; ++ni)
                    acc[mi][ni] = __builtin_amdgcn_mfma_f32_16x16x32_bf16(a[mi][ks], b[ni], acc[mi][ni], 0, 0, 0);
        }

        unsigned short* dstp = (sec == 0) ? xl_bf : (sec == 1) ? xr_bf : sk_bf;
#pragma unroll
        for (int ni = 0; ni < 4; ++ni) {
            int cl = c0 + ni * 16 + li;
            float bias = (sec == 0) ? bl[cl] : (sec == 1) ? br[cl] : (bs[cl] + cb[cl]);
#pragma unroll
            for (int mi = 0; mi < 4; ++mi)
#pragma unroll
                for (int r = 0; r < 4; ++r) {
                    int row = r0 + mi * 16 + q * 4 + r;
                    if (row >= N_NODES) continue;
                    dstp[(size_t)row * 128 + cl] = bf16_rn(acc[mi][ni][r] + bias);
                }
        }
    }
}

// ---------------- GATv2 aggregation: one wave per node, edge loop unrolled x4 ----------------
#define EDGE_BODY(U, L, AX, AY)                                        \
    {                                                                  \
        float2 xl2 = unpk(U);                                          \
        float ex = xl2.x + xr2.x;                                      \
        float ey = xl2.y + xr2.y;                                      \
        float lx = fmaxf(ex, NEG_SLOPE * ex);                          \
        float ly = fmaxf(ey, NEG_SLOPE * ey);                          \
        float p = lx * at2.x + ly * at2.y;                             \
        p += __shfl_xor(p, 1);                                         \
        p += __shfl_xor(p, 2);                                         \
        p += __shfl_xor(p, 4);                                         \
        p += __shfl_xor(p, 8);                                         \
        float w = __expf(p);                                           \
        L += w;                                                        \
        AX = fmaf(xl2.x, w, AX);                                       \
        AY = fmaf(xl2.y, w, AY);                                       \
    }

__global__ __launch_bounds__(256) void agg_kernel(
    const unsigned* __restrict__ xlb, const unsigned* __restrict__ xrb,
    const unsigned* __restrict__ skb, const int* __restrict__ row_ptr,
    const int* __restrict__ srcs, const float* __restrict__ att,
    unsigned* __restrict__ out_bf, float* __restrict__ out_f,
    int write_bf, int do_relu, int do_norm) {
    int wave = (blockIdx.x * blockDim.x + threadIdx.x) >> 6;
    int lane = threadIdx.x & 63;
    if (wave >= N_NODES) return;
    const int n = wave;

    float2 xr2 = unpk(xrb[(size_t)n * 64 + lane]);
    float2 at2 = ((const float2*)att)[lane];

    float l0 = 0.f, l1 = 0.f, l2 = 0.f, l3 = 0.f;
    float ax0 = 0.f, ay0 = 0.f, ax1 = 0.f, ay1 = 0.f;
    float ax2 = 0.f, ay2 = 0.f, ax3 = 0.f, ay3 = 0.f;

    int beg = row_ptr[n], end = row_ptr[n + 1];
    int e = beg;
    for (; e + 4 <= end; e += 4) {
        int s0 = srcs[e], s1 = srcs[e + 1], s2 = srcs[e + 2], s3 = srcs[e + 3];
        unsigned u0 = xlb[(size_t)s0 * 64 + lane];
        unsigned u1 = xlb[(size_t)s1 * 64 + lane];
        unsigned u2 = xlb[(size_t)s2 * 64 + lane];
        unsigned u3 = xlb[(size_t)s3 * 64 + lane];
        EDGE_BODY(u0, l0, ax0, ay0);
        EDGE_BODY(u1, l1, ax1, ay1);
        EDGE_BODY(u2, l2, ax2, ay2);
        EDGE_BODY(u3, l3, ax3, ay3);
    }
    for (; e < end; ++e) {
        unsigned u = xlb[(size_t)srcs[e] * 64 + lane];
        EDGE_BODY(u, l0, ax0, ay0);
    }
    float l = (l0 + l1) + (l2 + l3);
    float accx = (ax0 + ax1) + (ax2 + ax3);
    float accy = (ay0 + ay1) + (ay2 + ay3);

    float inv = (l > 0.f) ? 1.f / l : 0.f;
    float2 sk = unpk(skb[(size_t)n * 64 + lane]);
    float ox = accx * inv + sk.x;
    float oy = accy * inv + sk.y;
    if (do_relu) {
        ox = fmaxf(ox, 0.f);
        oy = fmaxf(oy, 0.f);
    }
    if (do_norm) {
        float ss = ox * ox + oy * oy;
        for (int off = 1; off < 64; off <<= 1) ss += __shfl_xor(ss, off);
        float r = 1.0f / sqrtf(ss);
        ox *= r;
        oy *= r;
    }
    if (write_bf)
        out_bf[(size_t)n * 64 + lane] = pack_bf16(ox, oy);
    else
        ((float2*)out_f)[(size_t)n * 64 + lane] = make_float2(ox, oy);
}

// ---------------- launch ----------------
extern "C" void kernel_launch(void* const* d_in, const int* in_sizes, int n_in,
                              void* d_out, int out_size, void* d_ws, size_t ws_size,
                              hipStream_t stream) {
    const float* x = (const float*)d_in[0];
    const int* ei = (const int*)d_in[1];
    const int* src = ei;
    const int* dst = ei + N_EDGES;
    const float* W0 = (const float*)d_in[2];

    const float* f_p[8];
    const float* m_p[8];
    const float* l_p[8];
    for (int i = 0; i < 8; ++i) f_p[i] = (const float*)d_in[3 + i];
    for (int i = 0; i < 8; ++i) m_p[i] = (const float*)d_in[11 + i];
    for (int i = 0; i < 8; ++i) l_p[i] = (const float*)d_in[19 + i];
    // indices: 0=Wl 1=bl 2=Wr 3=br 4=att 5=cb 6=Ws 7=bs

    char* ws = (char*)d_ws;
    unsigned short* xl_bf = (unsigned short*)ws; ws += (size_t)N_NODES * 128 * 2;  // 25.6 MB
    unsigned short* xr_bf = (unsigned short*)ws; ws += (size_t)N_NODES * 128 * 2;
    unsigned short* sk_bf = (unsigned short*)ws; ws += (size_t)N_NODES * 128 * 2;
    unsigned short* h_bf = (unsigned short*)ws;  ws += (size_t)N_NODES * 128 * 2;
    int* row_ptr = (int*)ws;       ws += (size_t)(N_NODES + 1) * 4;
    int* cursor = (int*)ws;        ws += (size_t)N_NODES * 4;
    int* counts = (int*)ws;        ws += (size_t)N_NODES * 4;
    int* srcs = (int*)ws;          ws += (size_t)N_EDGES * 4;
    int* bsum = (int*)ws;          ws += (size_t)SCAN_NB * 4;
    int* boff = (int*)ws;          ws += (size_t)SCAN_NB * 4;
    unsigned short* wt_f = (unsigned short*)ws; ws += (size_t)384 * 32 * 2;
    unsigned short* wt_m = (unsigned short*)ws; ws += (size_t)384 * 128 * 2;
    unsigned short* wt_l = (unsigned short*)ws; ws += (size_t)384 * 128 * 2;

    hipMemsetAsync(counts, 0, (size_t)N_NODES * 4, stream);
    hist_kernel<<<(N_EDGES + 255) / 256, 256, 0, stream>>>(dst, counts);
    scan_partial<<<SCAN_NB, 256, 0, stream>>>(counts, bsum);
    scan_bsum<<<1, 128, 0, stream>>>(bsum, boff, row_ptr);
    scan_final<<<SCAN_NB, 256, 0, stream>>>(counts, boff, row_ptr, cursor);
    scatter_kernel<<<(N_EDGES + 255) / 256, 256, 0, stream>>>(src, dst, cursor, srcs);

    convert_w<32><<<(384 * 32 + 255) / 256, 256, 0, stream>>>(f_p[0], f_p[2], f_p[6], wt_f);
    convert_w<128><<<(384 * 128 + 255) / 256, 256, 0, stream>>>(m_p[0], m_p[2], m_p[6], wt_m);
    convert_w<128><<<(384 * 128 + 255) / 256, 256, 0, stream>>>(l_p[0], l_p[2], l_p[6], wt_l);

    h0_kernel<<<(N_NODES * 32) / 256, 256, 0, stream>>>(x, W0, h_bf);

    const int gmm = (N_NODES + 255) / 256;
    const int gagg = (N_NODES * 64) / 256;
    float* out = (float*)d_out;

    // layer f (din=32), relu
    mm3_mfma<32><<<gmm, 256, 0, stream>>>(h_bf, wt_f, f_p[1], f_p[3], f_p[7], f_p[5],
                                          xl_bf, xr_bf, sk_bf);
    agg_kernel<<<gagg, 256, 0, stream>>>((unsigned*)xl_bf, (unsigned*)xr_bf, (unsigned*)sk_bf,
                                         row_ptr, srcs, f_p[4],
                                         (unsigned*)h_bf, nullptr, 1, 1, 0);

    // 3x layer m (din=128, shared weights), relu
    for (int it = 0; it < 3; ++it) {
        mm3_mfma<128><<<gmm, 256, 0, stream>>>(h_bf, wt_m, m_p[1], m_p[3], m_p[7], m_p[5],
                                               xl_bf, xr_bf, sk_bf);
        agg_kernel<<<gagg, 256, 0, stream>>>((unsigned*)xl_bf, (unsigned*)xr_bf, (unsigned*)sk_bf,
                                             row_ptr, srcs, m_p[4],
                                             (unsigned*)h_bf, nullptr, 1, 1, 0);
    }

    // layer l (din=128), no relu, L2 normalize, write fp32 to d_out
    mm3_mfma<128><<<gmm, 256, 0, stream>>>(h_bf, wt_l, l_p[1], l_p[3], l_p[7], l_p[5],
                                           xl_bf, xr_bf, sk_bf);
    agg_kernel<<<gagg, 256, 0, stream>>>((unsigned*)xl_bf, (unsigned*)xr_bf, (unsigned*)sk_bf,
                                         row_ptr, srcs, l_p[4],
                                         nullptr, out, 0, 0, 1);
}

// Round 7
// 801.169 us; speedup vs baseline: 1.2598x; 1.2598x over previous
//
#include <hip/hip_runtime.h>
#include <hip/hip_bf16.h>
#include <math.h>

#define N_NODES 100000
#define N_EDGES 1000000
#define NEG_SLOPE 0.2f
#define SCAN_NB 98  // ceil(100000/1024)

typedef short v8s __attribute__((ext_vector_type(8)));
typedef float v4f __attribute__((ext_vector_type(4)));

__device__ inline unsigned pack_bf16(float a, float b) {
    unsigned ua = __float_as_uint(a);
    unsigned ub = __float_as_uint(b);
    ua = (ua + 0x7FFFu + ((ua >> 16) & 1u)) >> 16;
    ub = (ub + 0x7FFFu + ((ub >> 16) & 1u)) >> 16;
    return ua | (ub << 16);
}
__device__ inline unsigned short bf16_rn(float x) {
    unsigned u = __float_as_uint(x);
    u = (u + 0x7FFFu + ((u >> 16) & 1u)) >> 16;
    return (unsigned short)u;
}
__device__ inline void unpack8(uint4 u, float* f) {
    f[0] = __uint_as_float(u.x << 16); f[1] = __uint_as_float(u.x & 0xFFFF0000u);
    f[2] = __uint_as_float(u.y << 16); f[3] = __uint_as_float(u.y & 0xFFFF0000u);
    f[4] = __uint_as_float(u.z << 16); f[5] = __uint_as_float(u.z & 0xFFFF0000u);
    f[6] = __uint_as_float(u.w << 16); f[7] = __uint_as_float(u.w & 0xFFFF0000u);
}

// ---------------- CSR build ----------------
__global__ void hist_kernel(const int* __restrict__ dst, int* __restrict__ counts) {
    int e = blockIdx.x * blockDim.x + threadIdx.x;
    if (e < N_EDGES) atomicAdd(&counts[dst[e]], 1);
}

__global__ void scan_partial(const int* __restrict__ counts, int* __restrict__ bsum) {
    __shared__ int red[256];
    int b = blockIdx.x;
    int base = b * 1024;
    int s = 0;
    for (int i = threadIdx.x; i < 1024; i += 256) {
        int gi = base + i;
        s += (gi < N_NODES) ? counts[gi] : 0;
    }
    red[threadIdx.x] = s;
    __syncthreads();
    for (int off = 128; off > 0; off >>= 1) {
        if (threadIdx.x < off) red[threadIdx.x] += red[threadIdx.x + off];
        __syncthreads();
    }
    if (threadIdx.x == 0) bsum[b] = red[0];
}

__global__ void scan_bsum(const int* __restrict__ bsum, int* __restrict__ boff,
                          int* __restrict__ row_ptr) {
    __shared__ int s[128];
    int t = threadIdx.x;
    int v = (t < SCAN_NB) ? bsum[t] : 0;
    s[t] = v;
    __syncthreads();
    for (int off = 1; off < 128; off <<= 1) {
        int u = (t >= off) ? s[t - off] : 0;
        __syncthreads();
        s[t] += u;
        __syncthreads();
    }
    if (t < SCAN_NB) boff[t] = s[t] - v;
    if (t == 127) row_ptr[N_NODES] = s[127];
}

__global__ void scan_final(const int* __restrict__ counts, const int* __restrict__ boff,
                           int* __restrict__ row_ptr, int* __restrict__ cursor) {
    __shared__ int tsum[256];
    int b = blockIdx.x;
    int base = b * 1024;
    int v[4];
    int local = 0;
#pragma unroll
    for (int j = 0; j < 4; ++j) {
        int gi = base + threadIdx.x * 4 + j;
        v[j] = (gi < N_NODES) ? counts[gi] : 0;
        local += v[j];
    }
    tsum[threadIdx.x] = local;
    __syncthreads();
    for (int off = 1; off < 256; off <<= 1) {
        int u = (threadIdx.x >= off) ? tsum[threadIdx.x - off] : 0;
        __syncthreads();
        tsum[threadIdx.x] += u;
        __syncthreads();
    }
    int run = boff[b] + tsum[threadIdx.x] - local;
#pragma unroll
    for (int j = 0; j < 4; ++j) {
        int gi = base + threadIdx.x * 4 + j;
        if (gi < N_NODES) {
            row_ptr[gi] = run;
            cursor[gi] = run;
            run += v[j];
        }
    }
}

__global__ void scatter_kernel(const int* __restrict__ src, const int* __restrict__ dst,
                               int* __restrict__ cursor, int* __restrict__ srcs) {
    int e = blockIdx.x * blockDim.x + threadIdx.x;
    if (e < N_EDGES) {
        int pos = atomicAdd(&cursor[dst[e]], 1);
        srcs[pos] = src[e];
    }
}

// ---------------- weight convert: Wt[n=0..383][k] = W_sec[k*128 + n&127] (bf16)
template <int K>
__global__ void convert_w(const float* __restrict__ Wl, const float* __restrict__ Wr,
                          const float* __restrict__ Ws, unsigned short* __restrict__ wt) {
    int idx = blockIdx.x * blockDim.x + threadIdx.x;
    if (idx >= 384 * K) return;
    int n = idx / K;
    int k = idx - n * K;
    int sec = n >> 7;
    int nn = n & 127;
    const float* W = (sec == 0) ? Wl : (sec == 1) ? Wr : Ws;
    wt[idx] = bf16_rn(W[k * 128 + nn]);
}

// ---------------- h0 = relu(x @ W0) -> bf16 [N,32] ----------------
__global__ void h0_kernel(const float* __restrict__ x, const float* __restrict__ W0,
                          unsigned short* __restrict__ h) {
    int tid = blockIdx.x * blockDim.x + threadIdx.x;
    int col = tid & 31;
    int row = tid >> 5;
    if (row >= N_NODES) return;
    const float* xr = x + row * 64;
    float acc = 0.f;
#pragma unroll
    for (int k = 0; k < 64; ++k) acc = fmaf(xr[k], W0[k * 32 + col], acc);
    h[row * 32 + col] = bf16_rn(fmaxf(acc, 0.f));
}

// ---------------- MFMA mm3: [N,K]bf16 @ Wt^T -> xl|xr|skip all bf16 ----------------
// One block = 256 rows (4 waves x 64 rows). A-frags loaded once into registers.
// MFMA operands SWAPPED (weights as A, nodes as B): D holds node rows in the
// lane dim -> each lane owns 4 consecutive channels of one row -> 8-byte packed
// stores in 32-B row segments (write-combine friendly; kills the 1.84x write amp).
template <int K>
__global__ __launch_bounds__(256) void mm3_mfma(
    const unsigned short* __restrict__ A, const unsigned short* __restrict__ Wt,
    const float* __restrict__ bl, const float* __restrict__ br, const float* __restrict__ bs,
    const float* __restrict__ cb,
    unsigned short* __restrict__ xl_bf, unsigned short* __restrict__ xr_bf,
    unsigned short* __restrict__ sk_bf) {
    const int tid = threadIdx.x;
    const int wave = tid >> 6;
    const int lane = tid & 63;
    const int q = lane >> 4;
    const int li = lane & 15;
    const int r0 = blockIdx.x * 256 + wave * 64;
    constexpr int KS = K / 32;

    // node fragments for 64 rows x K (B-operand layout: lane&15 = row, q*8 = k)
    v8s a[4][KS];
#pragma unroll
    for (int mi = 0; mi < 4; ++mi) {
        int row = r0 + mi * 16 + li;
        row = row < N_NODES ? row : N_NODES - 1;
#pragma unroll
        for (int ks = 0; ks < KS; ++ks)
            a[mi][ks] = *(const v8s*)&A[(size_t)row * K + ks * 32 + q * 8];
    }

    for (int t = 0; t < 6; ++t) {
        const int sec = t >> 1;
        const int c0 = (t & 1) * 64;
        v4f acc[4][4];
#pragma unroll
        for (int mi = 0; mi < 4; ++mi)
#pragma unroll
            for (int ni = 0; ni < 4; ++ni) acc[mi][ni] = (v4f)(0.f);

#pragma unroll
        for (int ks = 0; ks < KS; ++ks) {
            v8s b[4];
#pragma unroll
            for (int ni = 0; ni < 4; ++ni) {
                int col = sec * 128 + c0 + ni * 16 + li;
                b[ni] = *(const v8s*)&Wt[(size_t)col * K + ks * 32 + q * 8];
            }
            // swapped operands: D[w_col][node_row]
#pragma unroll
            for (int mi = 0; mi < 4; ++mi)
#pragma unroll
                for (int ni = 0; ni < 4; ++ni)
                    acc[mi][ni] = __builtin_amdgcn_mfma_f32_16x16x32_bf16(b[ni], a[mi][ks], acc[mi][ni], 0, 0, 0);
        }

        unsigned short* dstp = (sec == 0) ? xl_bf : (sec == 1) ? xr_bf : sk_bf;
#pragma unroll
        for (int ni = 0; ni < 4; ++ni) {
            int cbase = c0 + ni * 16 + q * 4;  // 4 consecutive cols per lane
            float4 b4;
            if (sec == 0) b4 = *(const float4*)&bl[cbase];
            else if (sec == 1) b4 = *(const float4*)&br[cbase];
            else {
                float4 t1 = *(const float4*)&bs[cbase];
                float4 t2 = *(const float4*)&cb[cbase];
                b4 = make_float4(t1.x + t2.x, t1.y + t2.y, t1.z + t2.z, t1.w + t2.w);
            }
#pragma unroll
            for (int mi = 0; mi < 4; ++mi) {
                int row = r0 + mi * 16 + li;
                if (row >= N_NODES) continue;
                v4f v = acc[mi][ni];
                uint2 pk;
                pk.x = pack_bf16(v[0] + b4.x, v[1] + b4.y);
                pk.y = pack_bf16(v[2] + b4.z, v[3] + b4.w);
                *(uint2*)&dstp[(size_t)row * 128 + cbase] = pk;
            }
        }
    }
}

// ---------------- GATv2 aggregation ----------------
// One wave per node. 4 groups of 16 lanes; group g handles edges e ≡ g (mod 4);
// lane li holds channels li*8..li*8+7 (all in head li>>2). One dwordx4 gathers a
// full 256-B xl row per group. Head-dot reduce = 2 shuffle steps (4-lane cluster).
__global__ __launch_bounds__(256) void agg_kernel(
    const uint4* __restrict__ xlb4, const uint4* __restrict__ xrb4,
    const uint4* __restrict__ skb4, const int* __restrict__ row_ptr,
    const int* __restrict__ srcs, const float* __restrict__ att,
    uint4* __restrict__ out_bf, float* __restrict__ out_f,
    int write_bf, int do_relu, int do_norm) {
    int n = (blockIdx.x * blockDim.x + threadIdx.x) >> 6;
    if (n >= N_NODES) return;
    int lane = threadIdx.x & 63;
    int g = lane >> 4, li = lane & 15;

    uint4 xru = xrb4[(size_t)n * 16 + li];
    float xr_f[8];
    unpack8(xru, xr_f);
    float at_f[8];
    *(float4*)&at_f[0] = *(const float4*)&att[li * 8];
    *(float4*)&at_f[4] = *(const float4*)&att[li * 8 + 4];

    float acc[8];
#pragma unroll
    for (int i = 0; i < 8; ++i) acc[i] = 0.f;
    float lsum = 0.f;

    int beg = row_ptr[n], end = row_ptr[n + 1];
    if (beg < end) {
        int e0 = beg + g;
        int idx = e0 < end ? e0 : end - 1;
        int s = srcs[idx];
        uint4 xp = xlb4[(size_t)s * 16 + li];
        for (int cb = beg; cb < end; cb += 4) {
            uint4 cur = xp;
            bool valid = (cb + g) < end;
            int en = cb + 4 + g;
            if (en < end) {
                int s2 = srcs[en];
                xp = xlb4[(size_t)s2 * 16 + li];
            }
            float xf[8];
            unpack8(cur, xf);
            float p = 0.f;
#pragma unroll
            for (int i = 0; i < 8; ++i) {
                float e_ = xf[i] + xr_f[i];
                float lk = fmaxf(e_, NEG_SLOPE * e_);
                p = fmaf(lk, at_f[i], p);
            }
            p += __shfl_xor(p, 1);
            p += __shfl_xor(p, 2);
            float w = valid ? __expf(p) : 0.f;  // scores O(0.1): no max-sub needed
            lsum += w;
#pragma unroll
            for (int i = 0; i < 8; ++i) acc[i] = fmaf(xf[i], w, acc[i]);
        }
    }
    // merge the 4 group-partials
#pragma unroll
    for (int i = 0; i < 8; ++i) {
        acc[i] += __shfl_xor(acc[i], 16);
        acc[i] += __shfl_xor(acc[i], 32);
    }
    lsum += __shfl_xor(lsum, 16);
    lsum += __shfl_xor(lsum, 32);

    float inv = (lsum > 0.f) ? 1.f / lsum : 0.f;
    uint4 sku = skb4[(size_t)n * 16 + li];
    float sk_f[8];
    unpack8(sku, sk_f);
    float o[8];
#pragma unroll
    for (int i = 0; i < 8; ++i) o[i] = fmaf(acc[i], inv, sk_f[i]);
    if (do_relu) {
#pragma unroll
        for (int i = 0; i < 8; ++i) o[i] = fmaxf(o[i], 0.f);
    }
    if (do_norm) {
        float ss = 0.f;
#pragma unroll
        for (int i = 0; i < 8; ++i) ss = fmaf(o[i], o[i], ss);
        ss += __shfl_xor(ss, 1);
        ss += __shfl_xor(ss, 2);
        ss += __shfl_xor(ss, 4);
        ss += __shfl_xor(ss, 8);
        float r = 1.0f / sqrtf(ss);
#pragma unroll
        for (int i = 0; i < 8; ++i) o[i] *= r;
    }
    if (g == 0) {
        if (write_bf) {
            uint4 pk;
            pk.x = pack_bf16(o[0], o[1]);
            pk.y = pack_bf16(o[2], o[3]);
            pk.z = pack_bf16(o[4], o[5]);
            pk.w = pack_bf16(o[6], o[7]);
            out_bf[(size_t)n * 16 + li] = pk;
        } else {
            *(float4*)&out_f[(size_t)n * 128 + li * 8] = make_float4(o[0], o[1], o[2], o[3]);
            *(float4*)&out_f[(size_t)n * 128 + li * 8 + 4] = make_float4(o[4], o[5], o[6], o[7]);
        }
    }
}

// ---------------- launch ----------------
extern "C" void kernel_launch(void* const* d_in, const int* in_sizes, int n_in,
                              void* d_out, int out_size, void* d_ws, size_t ws_size,
                              hipStream_t stream) {
    const float* x = (const float*)d_in[0];
    const int* ei = (const int*)d_in[1];
    const int* src = ei;
    const int* dst = ei + N_EDGES;
    const float* W0 = (const float*)d_in[2];

    const float* f_p[8];
    const float* m_p[8];
    const float* l_p[8];
    for (int i = 0; i < 8; ++i) f_p[i] = (const float*)d_in[3 + i];
    for (int i = 0; i < 8; ++i) m_p[i] = (const float*)d_in[11 + i];
    for (int i = 0; i < 8; ++i) l_p[i] = (const float*)d_in[19 + i];
    // indices: 0=Wl 1=bl 2=Wr 3=br 4=att 5=cb 6=Ws 7=bs

    char* ws = (char*)d_ws;
    unsigned short* xl_bf = (unsigned short*)ws; ws += (size_t)N_NODES * 128 * 2;  // 25.6 MB
    unsigned short* xr_bf = (unsigned short*)ws; ws += (size_t)N_NODES * 128 * 2;
    unsigned short* sk_bf = (unsigned short*)ws; ws += (size_t)N_NODES * 128 * 2;
    unsigned short* h_bf = (unsigned short*)ws;  ws += (size_t)N_NODES * 128 * 2;
    int* row_ptr = (int*)ws;       ws += (size_t)(N_NODES + 1) * 4;
    int* cursor = (int*)ws;        ws += (size_t)N_NODES * 4;
    int* counts = (int*)ws;        ws += (size_t)N_NODES * 4;
    int* srcs = (int*)ws;          ws += (size_t)N_EDGES * 4;
    int* bsum = (int*)ws;          ws += (size_t)SCAN_NB * 4;
    int* boff = (int*)ws;          ws += (size_t)SCAN_NB * 4;
    unsigned short* wt_f = (unsigned short*)ws; ws += (size_t)384 * 32 * 2;
    unsigned short* wt_m = (unsigned short*)ws; ws += (size_t)384 * 128 * 2;
    unsigned short* wt_l = (unsigned short*)ws; ws += (size_t)384 * 128 * 2;

    hipMemsetAsync(counts, 0, (size_t)N_NODES * 4, stream);
    hist_kernel<<<(N_EDGES + 255) / 256, 256, 0, stream>>>(dst, counts);
    scan_partial<<<SCAN_NB, 256, 0, stream>>>(counts, bsum);
    scan_bsum<<<1, 128, 0, stream>>>(bsum, boff, row_ptr);
    scan_final<<<SCAN_NB, 256, 0, stream>>>(counts, boff, row_ptr, cursor);
    scatter_kernel<<<(N_EDGES + 255) / 256, 256, 0, stream>>>(src, dst, cursor, srcs);

    convert_w<32><<<(384 * 32 + 255) / 256, 256, 0, stream>>>(f_p[0], f_p[2], f_p[6], wt_f);
    convert_w<128><<<(384 * 128 + 255) / 256, 256, 0, stream>>>(m_p[0], m_p[2], m_p[6], wt_m);
    convert_w<128><<<(384 * 128 + 255) / 256, 256, 0, stream>>>(l_p[0], l_p[2], l_p[6], wt_l);

    h0_kernel<<<(N_NODES * 32) / 256, 256, 0, stream>>>(x, W0, h_bf);

    const int gmm = (N_NODES + 255) / 256;
    const int gagg = (N_NODES * 64) / 256;
    float* out = (float*)d_out;

    // layer f (din=32), relu
    mm3_mfma<32><<<gmm, 256, 0, stream>>>(h_bf, wt_f, f_p[1], f_p[3], f_p[7], f_p[5],
                                          xl_bf, xr_bf, sk_bf);
    agg_kernel<<<gagg, 256, 0, stream>>>((uint4*)xl_bf, (uint4*)xr_bf, (uint4*)sk_bf,
                                         row_ptr, srcs, f_p[4],
                                         (uint4*)h_bf, nullptr, 1, 1, 0);

    // 3x layer m (din=128, shared weights), relu
    for (int it = 0; it < 3; ++it) {
        mm3_mfma<128><<<gmm, 256, 0, stream>>>(h_bf, wt_m, m_p[1], m_p[3], m_p[7], m_p[5],
                                               xl_bf, xr_bf, sk_bf);
        agg_kernel<<<gagg, 256, 0, stream>>>((uint4*)xl_bf, (uint4*)xr_bf, (uint4*)sk_bf,
                                             row_ptr, srcs, m_p[4],
                                             (uint4*)h_bf, nullptr, 1, 1, 0);
    }

    // layer l (din=128), no relu, L2 normalize, write fp32 to d_out
    mm3_mfma<128><<<gmm, 256, 0, stream>>>(h_bf, wt_l, l_p[1], l_p[3], l_p[7], l_p[5],
                                           xl_bf, xr_bf, sk_bf);
    agg_kernel<<<gagg, 256, 0, stream>>>((uint4*)xl_bf, (uint4*)xr_bf, (uint4*)sk_bf,
                                         row_ptr, srcs, l_p[4],
                                         nullptr, out, 0, 0, 1);
}

// Round 8
// 734.445 us; speedup vs baseline: 1.3742x; 1.0908x over previous
//
#include <hip/hip_runtime.h>
#include <hip/hip_bf16.h>
#include <math.h>

#define N_NODES 100000
#define N_EDGES 1000000
#define NEG_SLOPE 0.2f
#define NBUCK 98        // ceil(100000/1024) node buckets
#define BSHIFT 10       // 1024 nodes per bucket
#define SLAB 12288      // slab capacity per bucket (mean 10240, sigma ~101 -> 20 sigma headroom)
#define BINA_EDGES 4096

typedef short v8s __attribute__((ext_vector_type(8)));
typedef float v4f __attribute__((ext_vector_type(4)));

__device__ inline unsigned pack_bf16(float a, float b) {
    unsigned ua = __float_as_uint(a);
    unsigned ub = __float_as_uint(b);
    ua = (ua + 0x7FFFu + ((ua >> 16) & 1u)) >> 16;
    ub = (ub + 0x7FFFu + ((ub >> 16) & 1u)) >> 16;
    return ua | (ub << 16);
}
__device__ inline unsigned short bf16_rn(float x) {
    unsigned u = __float_as_uint(x);
    u = (u + 0x7FFFu + ((u >> 16) & 1u)) >> 16;
    return (unsigned short)u;
}
__device__ inline void unpack8(uint4 u, float* f) {
    f[0] = __uint_as_float(u.x << 16); f[1] = __uint_as_float(u.x & 0xFFFF0000u);
    f[2] = __uint_as_float(u.y << 16); f[3] = __uint_as_float(u.y & 0xFFFF0000u);
    f[4] = __uint_as_float(u.z << 16); f[5] = __uint_as_float(u.z & 0xFFFF0000u);
    f[6] = __uint_as_float(u.w << 16); f[7] = __uint_as_float(u.w & 0xFFFF0000u);
}

// ---------------- CSR build: two-level LDS-binned counting sort ----------------
__global__ void init_cursors(int* __restrict__ gcursor) {
    int t = blockIdx.x * blockDim.x + threadIdx.x;
    if (t < NBUCK) gcursor[t] = t * SLAB;
}

// Pass A: bin edges into 98 coarse buckets (1024 nodes each). One global atomic
// per (block,bucket); writes staged in LDS and flushed in address-monotone bursts.
__global__ __launch_bounds__(256) void binA_kernel(
    const int* __restrict__ src, const int* __restrict__ dst,
    int* __restrict__ gcursor, int* __restrict__ tmp) {
    __shared__ int bstart[NBUCK];
    __shared__ int addrbase[NBUCK];
    __shared__ int bcur[NBUCK];
    __shared__ int s[256];
    __shared__ int staged_val[BINA_EDGES];
    __shared__ int staged_addr[BINA_EDGES];
    const int tid = threadIdx.x;
    const int base = blockIdx.x * BINA_EDGES;
    const int ecount = min(BINA_EDGES, N_EDGES - base);

    if (tid < NBUCK) bcur[tid] = 0;
    __syncthreads();
    for (int j = tid; j < ecount; j += 256) {
        int d = dst[base + j];
        atomicAdd(&bcur[d >> BSHIFT], 1);
    }
    __syncthreads();
    int own = (tid < NBUCK) ? bcur[tid] : 0;
    s[tid] = own;
    __syncthreads();
    for (int off = 1; off < 256; off <<= 1) {
        int u = (tid >= off) ? s[tid - off] : 0;
        __syncthreads();
        s[tid] += u;
        __syncthreads();
    }
    if (tid < NBUCK) {
        int excl = s[tid] - own;
        bstart[tid] = excl;
        int resv = atomicAdd(&gcursor[tid], own);
        addrbase[tid] = resv - excl;
    }
    __syncthreads();
    if (tid < NBUCK) bcur[tid] = bstart[tid];
    __syncthreads();
    for (int j = tid; j < ecount; j += 256) {
        int d = dst[base + j];
        int sr = src[base + j];
        int bk = d >> BSHIFT;
        int lpos = atomicAdd(&bcur[bk], 1);
        staged_val[lpos] = ((d & ((1 << BSHIFT) - 1)) << 17) | sr;
        staged_addr[lpos] = addrbase[bk] + lpos;
    }
    __syncthreads();
    for (int j = tid; j < ecount; j += 256)
        tmp[staged_addr[j]] = staged_val[j];
}

// tiny scan over the 98 bucket sizes -> bucket bases in final srcs
__global__ void bucket_scan(const int* __restrict__ gcursor, int* __restrict__ bbase,
                            int* __restrict__ row_ptr) {
    __shared__ int s[128];
    int t = threadIdx.x;
    int v = (t < NBUCK) ? (gcursor[t] - t * SLAB) : 0;
    s[t] = v;
    __syncthreads();
    for (int off = 1; off < 128; off <<= 1) {
        int u = (t >= off) ? s[t - off] : 0;
        __syncthreads();
        s[t] += u;
        __syncthreads();
    }
    if (t < NBUCK) bbase[t] = s[t] - v;
    if (t == 0) row_ptr[N_NODES] = N_EDGES;
}

// Pass B: one block per bucket. LDS hist+scan over its 1024 nodes -> row_ptr,
// then scatter srcs into the bucket's private contiguous region (single-XCD writes).
__global__ __launch_bounds__(256) void binB_kernel(
    const int* __restrict__ tmp, const int* __restrict__ gcursor,
    const int* __restrict__ bbase, int* __restrict__ row_ptr,
    int* __restrict__ srcs) {
    __shared__ int hist[1024];
    __shared__ int tsum[256];
    const int b = blockIdx.x;
    const int tid = threadIdx.x;
    const int base = b * SLAB;
    const int cnt = gcursor[b] - base;
    const int node0 = b << BSHIFT;
    const int nodes_in = min(1024, N_NODES - node0);
    const int gb = bbase[b];

    for (int i = tid; i < 1024; i += 256) hist[i] = 0;
    __syncthreads();
    for (int i = tid; i < cnt; i += 256)
        atomicAdd(&hist[tmp[base + i] >> 17], 1);
    __syncthreads();
    int v[4], local = 0;
#pragma unroll
    for (int j = 0; j < 4; ++j) {
        v[j] = hist[tid * 4 + j];
        local += v[j];
    }
    tsum[tid] = local;
    __syncthreads();
    for (int off = 1; off < 256; off <<= 1) {
        int u = (tid >= off) ? tsum[tid - off] : 0;
        __syncthreads();
        tsum[tid] += u;
        __syncthreads();
    }
    int run = tsum[tid] - local;
#pragma unroll
    for (int j = 0; j < 4; ++j) {
        hist[tid * 4 + j] = run;
        run += v[j];
    }
    __syncthreads();
    for (int i = tid; i < nodes_in; i += 256)
        row_ptr[node0 + i] = gb + hist[i];
    __syncthreads();
    for (int i = tid; i < cnt; i += 256) {
        int e = tmp[base + i];
        int pos = atomicAdd(&hist[e >> 17], 1);
        srcs[gb + pos] = e & 0x1FFFF;
    }
}

// ---------------- weight convert: Wt[n=0..383][k] = W_sec[k*128 + n&127] (bf16)
template <int K>
__global__ void convert_w(const float* __restrict__ Wl, const float* __restrict__ Wr,
                          const float* __restrict__ Ws, unsigned short* __restrict__ wt) {
    int idx = blockIdx.x * blockDim.x + threadIdx.x;
    if (idx >= 384 * K) return;
    int n = idx / K;
    int k = idx - n * K;
    int sec = n >> 7;
    int nn = n & 127;
    const float* W = (sec == 0) ? Wl : (sec == 1) ? Wr : Ws;
    wt[idx] = bf16_rn(W[k * 128 + nn]);
}

// ---------------- h0 = relu(x @ W0) -> bf16 [N,32] ----------------
__global__ void h0_kernel(const float* __restrict__ x, const float* __restrict__ W0,
                          unsigned short* __restrict__ h) {
    int tid = blockIdx.x * blockDim.x + threadIdx.x;
    int col = tid & 31;
    int row = tid >> 5;
    if (row >= N_NODES) return;
    const float* xr = x + row * 64;
    float acc = 0.f;
#pragma unroll
    for (int k = 0; k < 64; ++k) acc = fmaf(xr[k], W0[k * 32 + col], acc);
    h[row * 32 + col] = bf16_rn(fmaxf(acc, 0.f));
}

// ---------------- MFMA mm3: [N,K]bf16 @ Wt^T -> xl|xr|skip all bf16 ----------------
template <int K>
__global__ __launch_bounds__(256) void mm3_mfma(
    const unsigned short* __restrict__ A, const unsigned short* __restrict__ Wt,
    const float* __restrict__ bl, const float* __restrict__ br, const float* __restrict__ bs,
    const float* __restrict__ cb,
    unsigned short* __restrict__ xl_bf, unsigned short* __restrict__ xr_bf,
    unsigned short* __restrict__ sk_bf) {
    const int tid = threadIdx.x;
    const int wave = tid >> 6;
    const int lane = tid & 63;
    const int q = lane >> 4;
    const int li = lane & 15;
    const int r0 = blockIdx.x * 256 + wave * 64;
    constexpr int KS = K / 32;

    v8s a[4][KS];
#pragma unroll
    for (int mi = 0; mi < 4; ++mi) {
        int row = r0 + mi * 16 + li;
        row = row < N_NODES ? row : N_NODES - 1;
#pragma unroll
        for (int ks = 0; ks < KS; ++ks)
            a[mi][ks] = *(const v8s*)&A[(size_t)row * K + ks * 32 + q * 8];
    }

    for (int t = 0; t < 6; ++t) {
        const int sec = t >> 1;
        const int c0 = (t & 1) * 64;
        v4f acc[4][4];
#pragma unroll
        for (int mi = 0; mi < 4; ++mi)
#pragma unroll
            for (int ni = 0; ni < 4; ++ni) acc[mi][ni] = (v4f)(0.f);

#pragma unroll
        for (int ks = 0; ks < KS; ++ks) {
            v8s b[4];
#pragma unroll
            for (int ni = 0; ni < 4; ++ni) {
                int col = sec * 128 + c0 + ni * 16 + li;
                b[ni] = *(const v8s*)&Wt[(size_t)col * K + ks * 32 + q * 8];
            }
#pragma unroll
            for (int mi = 0; mi < 4; ++mi)
#pragma unroll
                for (int ni = 0; ni < 4; ++ni)
                    acc[mi][ni] = __builtin_amdgcn_mfma_f32_16x16x32_bf16(b[ni], a[mi][ks], acc[mi][ni], 0, 0, 0);
        }

        unsigned short* dstp = (sec == 0) ? xl_bf : (sec == 1) ? xr_bf : sk_bf;
#pragma unroll
        for (int ni = 0; ni < 4; ++ni) {
            int cbase = c0 + ni * 16 + q * 4;
            float4 b4;
            if (sec == 0) b4 = *(const float4*)&bl[cbase];
            else if (sec == 1) b4 = *(const float4*)&br[cbase];
            else {
                float4 t1 = *(const float4*)&bs[cbase];
                float4 t2 = *(const float4*)&cb[cbase];
                b4 = make_float4(t1.x + t2.x, t1.y + t2.y, t1.z + t2.z, t1.w + t2.w);
            }
#pragma unroll
            for (int mi = 0; mi < 4; ++mi) {
                int row = r0 + mi * 16 + li;
                if (row >= N_NODES) continue;
                v4f v = acc[mi][ni];
                uint2 pk;
                pk.x = pack_bf16(v[0] + b4.x, v[1] + b4.y);
                pk.y = pack_bf16(v[2] + b4.z, v[3] + b4.w);
                *(uint2*)&dstp[(size_t)row * 128 + cbase] = pk;
            }
        }
    }
}

// ---------------- GATv2 aggregation ----------------
__global__ __launch_bounds__(256) void agg_kernel(
    const uint4* __restrict__ xlb4, const uint4* __restrict__ xrb4,
    const uint4* __restrict__ skb4, const int* __restrict__ row_ptr,
    const int* __restrict__ srcs, const float* __restrict__ att,
    uint4* __restrict__ out_bf, float* __restrict__ out_f,
    int write_bf, int do_relu, int do_norm) {
    int n = (blockIdx.x * blockDim.x + threadIdx.x) >> 6;
    if (n >= N_NODES) return;
    int lane = threadIdx.x & 63;
    int g = lane >> 4, li = lane & 15;

    uint4 xru = xrb4[(size_t)n * 16 + li];
    float xr_f[8];
    unpack8(xru, xr_f);
    float at_f[8];
    *(float4*)&at_f[0] = *(const float4*)&att[li * 8];
    *(float4*)&at_f[4] = *(const float4*)&att[li * 8 + 4];

    float acc[8];
#pragma unroll
    for (int i = 0; i < 8; ++i) acc[i] = 0.f;
    float lsum = 0.f;

    int beg = row_ptr[n], end = row_ptr[n + 1];
    if (beg < end) {
        int e0 = beg + g;
        int idx = e0 < end ? e0 : end - 1;
        int s = srcs[idx];
        uint4 xp = xlb4[(size_t)s * 16 + li];
        for (int cb = beg; cb < end; cb += 4) {
            uint4 cur = xp;
            bool valid = (cb + g) < end;
            int en = cb + 4 + g;
            if (en < end) {
                int s2 = srcs[en];
                xp = xlb4[(size_t)s2 * 16 + li];
            }
            float xf[8];
            unpack8(cur, xf);
            float p = 0.f;
#pragma unroll
            for (int i = 0; i < 8; ++i) {
                float e_ = xf[i] + xr_f[i];
                float lk = fmaxf(e_, NEG_SLOPE * e_);
                p = fmaf(lk, at_f[i], p);
            }
            p += __shfl_xor(p, 1);
            p += __shfl_xor(p, 2);
            float w = valid ? __expf(p) : 0.f;
            lsum += w;
#pragma unroll
            for (int i = 0; i < 8; ++i) acc[i] = fmaf(xf[i], w, acc[i]);
        }
    }
#pragma unroll
    for (int i = 0; i < 8; ++i) {
        acc[i] += __shfl_xor(acc[i], 16);
        acc[i] += __shfl_xor(acc[i], 32);
    }
    lsum += __shfl_xor(lsum, 16);
    lsum += __shfl_xor(lsum, 32);

    float inv = (lsum > 0.f) ? 1.f / lsum : 0.f;
    uint4 sku = skb4[(size_t)n * 16 + li];
    float sk_f[8];
    unpack8(sku, sk_f);
    float o[8];
#pragma unroll
    for (int i = 0; i < 8; ++i) o[i] = fmaf(acc[i], inv, sk_f[i]);
    if (do_relu) {
#pragma unroll
        for (int i = 0; i < 8; ++i) o[i] = fmaxf(o[i], 0.f);
    }
    if (do_norm) {
        float ss = 0.f;
#pragma unroll
        for (int i = 0; i < 8; ++i) ss = fmaf(o[i], o[i], ss);
        ss += __shfl_xor(ss, 1);
        ss += __shfl_xor(ss, 2);
        ss += __shfl_xor(ss, 4);
        ss += __shfl_xor(ss, 8);
        float r = 1.0f / sqrtf(ss);
#pragma unroll
        for (int i = 0; i < 8; ++i) o[i] *= r;
    }
    if (g == 0) {
        if (write_bf) {
            uint4 pk;
            pk.x = pack_bf16(o[0], o[1]);
            pk.y = pack_bf16(o[2], o[3]);
            pk.z = pack_bf16(o[4], o[5]);
            pk.w = pack_bf16(o[6], o[7]);
            out_bf[(size_t)n * 16 + li] = pk;
        } else {
            *(float4*)&out_f[(size_t)n * 128 + li * 8] = make_float4(o[0], o[1], o[2], o[3]);
            *(float4*)&out_f[(size_t)n * 128 + li * 8 + 4] = make_float4(o[4], o[5], o[6], o[7]);
        }
    }
}

// ---------------- launch ----------------
extern "C" void kernel_launch(void* const* d_in, const int* in_sizes, int n_in,
                              void* d_out, int out_size, void* d_ws, size_t ws_size,
                              hipStream_t stream) {
    const float* x = (const float*)d_in[0];
    const int* ei = (const int*)d_in[1];
    const int* src = ei;
    const int* dst = ei + N_EDGES;
    const float* W0 = (const float*)d_in[2];

    const float* f_p[8];
    const float* m_p[8];
    const float* l_p[8];
    for (int i = 0; i < 8; ++i) f_p[i] = (const float*)d_in[3 + i];
    for (int i = 0; i < 8; ++i) m_p[i] = (const float*)d_in[11 + i];
    for (int i = 0; i < 8; ++i) l_p[i] = (const float*)d_in[19 + i];
    // indices: 0=Wl 1=bl 2=Wr 3=br 4=att 5=cb 6=Ws 7=bs

    char* ws = (char*)d_ws;
    unsigned short* xl_bf = (unsigned short*)ws; ws += (size_t)N_NODES * 128 * 2;  // 25.6 MB
    unsigned short* xr_bf = (unsigned short*)ws; ws += (size_t)N_NODES * 128 * 2;
    unsigned short* sk_bf = (unsigned short*)ws; ws += (size_t)N_NODES * 128 * 2;
    unsigned short* h_bf = (unsigned short*)ws;  ws += (size_t)N_NODES * 128 * 2;
    int* row_ptr = (int*)ws;       ws += (size_t)(N_NODES + 1) * 4;
    int* srcs = (int*)ws;          ws += (size_t)N_EDGES * 4;
    int* tmp = (int*)ws;           ws += (size_t)NBUCK * SLAB * 4;   // 4.8 MB slabs
    int* gcursor = (int*)ws;       ws += (size_t)NBUCK * 4;
    int* bbase = (int*)ws;         ws += (size_t)NBUCK * 4;
    unsigned short* wt_f = (unsigned short*)ws; ws += (size_t)384 * 32 * 2;
    unsigned short* wt_m = (unsigned short*)ws; ws += (size_t)384 * 128 * 2;
    unsigned short* wt_l = (unsigned short*)ws; ws += (size_t)384 * 128 * 2;

    // CSR build (two-level binned counting sort)
    init_cursors<<<1, 128, 0, stream>>>(gcursor);
    binA_kernel<<<(N_EDGES + BINA_EDGES - 1) / BINA_EDGES, 256, 0, stream>>>(src, dst, gcursor, tmp);
    bucket_scan<<<1, 128, 0, stream>>>(gcursor, bbase, row_ptr);
    binB_kernel<<<NBUCK, 256, 0, stream>>>(tmp, gcursor, bbase, row_ptr, srcs);

    convert_w<32><<<(384 * 32 + 255) / 256, 256, 0, stream>>>(f_p[0], f_p[2], f_p[6], wt_f);
    convert_w<128><<<(384 * 128 + 255) / 256, 256, 0, stream>>>(m_p[0], m_p[2], m_p[6], wt_m);
    convert_w<128><<<(384 * 128 + 255) / 256, 256, 0, stream>>>(l_p[0], l_p[2], l_p[6], wt_l);

    h0_kernel<<<(N_NODES * 32) / 256, 256, 0, stream>>>(x, W0, h_bf);

    const int gmm = (N_NODES + 255) / 256;
    const int gagg = (N_NODES * 64) / 256;
    float* out = (float*)d_out;

    // layer f (din=32), relu
    mm3_mfma<32><<<gmm, 256, 0, stream>>>(h_bf, wt_f, f_p[1], f_p[3], f_p[7], f_p[5],
                                          xl_bf, xr_bf, sk_bf);
    agg_kernel<<<gagg, 256, 0, stream>>>((uint4*)xl_bf, (uint4*)xr_bf, (uint4*)sk_bf,
                                         row_ptr, srcs, f_p[4],
                                         (uint4*)h_bf, nullptr, 1, 1, 0);

    // 3x layer m (din=128, shared weights), relu
    for (int it = 0; it < 3; ++it) {
        mm3_mfma<128><<<gmm, 256, 0, stream>>>(h_bf, wt_m, m_p[1], m_p[3], m_p[7], m_p[5],
                                               xl_bf, xr_bf, sk_bf);
        agg_kernel<<<gagg, 256, 0, stream>>>((uint4*)xl_bf, (uint4*)xr_bf, (uint4*)sk_bf,
                                             row_ptr, srcs, m_p[4],
                                             (uint4*)h_bf, nullptr, 1, 1, 0);
    }

    // layer l (din=128), no relu, L2 normalize, write fp32 to d_out
    mm3_mfma<128><<<gmm, 256, 0, stream>>>(h_bf, wt_l, l_p[1], l_p[3], l_p[7], l_p[5],
                                           xl_bf, xr_bf, sk_bf);
    agg_kernel<<<gagg, 256, 0, stream>>>((uint4*)xl_bf, (uint4*)xr_bf, (uint4*)sk_bf,
                                         row_ptr, srcs, l_p[4],
                                         nullptr, out, 0, 0, 1);
}